// Round 1
// baseline (3604.555 us; speedup 1.0000x reference)
//
#include <hip/hip_runtime.h>
#include <cstdint>

typedef unsigned short u16;
typedef __attribute__((ext_vector_type(8))) short s16x8;    // 8 bf16 (4 VGPRs)
typedef __attribute__((ext_vector_type(4))) float f32x4;    // 16x16 MFMA C/D frag
typedef __attribute__((ext_vector_type(16))) float f32x16;  // 32x32 MFMA C/D frag

#define T_LEN 256
#define BATCH 64
#define HID   1024
#define NWG   64

// ---------- bf16 helpers ----------
__device__ __forceinline__ float b2f(u16 u) {
    union { unsigned u; float f; } v; v.u = ((unsigned)u) << 16; return v.f;
}
__device__ __forceinline__ u16 f2b(float f) {
    union { float f; unsigned u; } v; v.f = f;
    unsigned u = v.u;
    return (u16)((u + 0x7fffu + ((u >> 16) & 1u)) >> 16);
}
__device__ __forceinline__ float sigmoidf_(float x) { return 1.0f / (1.0f + __expf(-x)); }
__device__ __forceinline__ float tanhf_(float x) {
    float e = __expf(2.0f * x);
    return 1.0f - 2.0f / (e + 1.0f);
}

// ---------- fp32 -> bf16 bulk convert ----------
__global__ __launch_bounds__(256) void f32_to_bf16(const float4* __restrict__ in,
                                                   ushort4* __restrict__ out, int n4) {
    int i = blockIdx.x * 256 + threadIdx.x;
    if (i < n4) {
        float4 v = in[i];
        ushort4 o;
        o.x = f2b(v.x); o.y = f2b(v.y); o.z = f2b(v.z); o.w = f2b(v.w);
        out[i] = o;
    }
}

// ---------- transpose 1024x1024: out_bf16[c][r] = (bf16)in_f32[r][c] ----------
__global__ __launch_bounds__(256) void transpose_f32_bf16(const float* __restrict__ in,
                                                          u16* __restrict__ out) {
    __shared__ u16 tile[64][65];
    int tx = threadIdx.x & 63, ty = threadIdx.x >> 6;
    int r0 = blockIdx.y * 64, c0 = blockIdx.x * 64;
    for (int r = ty; r < 64; r += 4)
        tile[r][tx] = f2b(in[(size_t)(r0 + r) * 1024 + c0 + tx]);
    __syncthreads();
    for (int c = ty; c < 64; c += 4)
        out[(size_t)(c0 + c) * 1024 + r0 + tx] = tile[tx][c];
}

// ---------- init: counters, fused bias, HsBuf[0] = (bf16)H0 in Hp layout ----------
// Hp layout per step-chunk (65536 u16): off(b,k) = (k>>4)*1024 + b*16 + (k&15)
__global__ __launch_bounds__(256) void init_misc(const float* __restrict__ H0,
                                                 u16* __restrict__ HsBuf,
                                                 unsigned* __restrict__ cnt,
                                                 const float* __restrict__ b_i,
                                                 const float* __restrict__ b_f,
                                                 const float* __restrict__ b_o,
                                                 const float* __restrict__ b_c,
                                                 float* __restrict__ fbias) {
    int i = blockIdx.x * 256 + threadIdx.x;   // grid 256x256 = 65536
    if (i < 1024) cnt[i] = 0u;
    if (i < 4096) {
        int g = i >> 10, k = i & 1023;
        const float* bp = (g == 0) ? b_i : (g == 1) ? b_f : (g == 2) ? b_o : b_c;
        fbias[i] = bp[k];
    }
    if (i < BATCH * HID) {
        int b = i >> 10, k = i & 1023;
        HsBuf[(size_t)(k >> 4) * 1024 + b * 16 + (k & 15)] = f2b(H0[i]);
    }
}

// ---------- pack W_h (4 mats, [h][k] transposed layout) into MFMA-frag order ----
__global__ __launch_bounds__(256) void pack_wh(const u16* __restrict__ WThT,
                                               u16* __restrict__ Wpack) {
    size_t idx = (size_t)blockIdx.x * 256 + threadIdx.x;  // 0..524287
    int lane = idx & 63;
    int kc   = (idx >> 6) & 63;
    int ct   = (idx >> 12) & 1;
    int j    = (int)(idx >> 13);
    int ln = lane & 31, kh = lane >> 5;
    int col = ct * 32 + ln;
    int g = col >> 4, hi = col & 15;
    const uint4* src = (const uint4*)(WThT + (size_t)g * 1048576 +
                                      (size_t)(16 * j + hi) * 1024 + kc * 16 + kh * 8);
    ((uint4*)Wpack)[idx] = *src;
}

// ---------- GEMM: C[m][col] = A[m][:] . BT[col][:] + bias[col] ----------
// mode 0: Cf fp32 row-major [M][ldc].  mode 1: Cb bf16 permuted X layout
//   off(t,b,g,h) = t*262144 + (h>>4)*4096 + b*64 + g*16 + (h&15), row=t*64+b, col=g*1024+h
// aperm: A is in Hp layout (per-64-row chunk of 65536 u16, off = (k>>4)*1024 + b*16 + (k&15))
__global__ __launch_bounds__(256) void gemm_bt(const u16* __restrict__ A,
                                               const u16* __restrict__ BT,
                                               const float* __restrict__ bias,
                                               u16* __restrict__ Cb,
                                               float* __restrict__ Cf,
                                               int M, int K, int ldc, int xperm, int aperm) {
    __shared__ __align__(16) u16 As[128 * 32];
    __shared__ __align__(16) u16 Bs[128 * 32];
    const int tid  = threadIdx.x;
    const int lane = tid & 63;
    const int w    = tid >> 6;
    const int wm   = (w >> 1) * 64;
    const int wn   = (w & 1) * 64;
    const long m0 = (long)blockIdx.x * 128;
    const long n0 = (long)blockIdx.y * 128;
    const int lrow = lane & 15;
    const int lq   = lane >> 4;

    f32x4 acc[4][4];
    const f32x4 vzero = {0.f, 0.f, 0.f, 0.f};
    #pragma unroll
    for (int i = 0; i < 4; ++i)
        #pragma unroll
        for (int j = 0; j < 4; ++j) acc[i][j] = vzero;

    for (int k0 = 0; k0 < K; k0 += 32) {
        __syncthreads();
        #pragma unroll
        for (int i = 0; i < 2; ++i) {
            int chunk = i * 256 + w * 64 + lane;
            const u16* ga;
            if (aperm) {
                long row = m0 + (chunk >> 2);
                int  c   = chunk & 3;
                ga = A + (row >> 6) * 65536L + (long)((k0 >> 4) + (c >> 1)) * 1024 +
                     (row & 63) * 16 + (c & 1) * 8;
            } else {
                ga = A + (m0 + (chunk >> 2)) * (long)K + k0 + (chunk & 3) * 8;
            }
            __builtin_amdgcn_global_load_lds(
                (const __attribute__((address_space(1))) unsigned int*)ga,
                (__attribute__((address_space(3))) unsigned int*)(As + (i * 256 + w * 64) * 8),
                16, 0, 0);
            const u16* gb = BT + (n0 + (chunk >> 2)) * (long)K + k0 + (chunk & 3) * 8;
            __builtin_amdgcn_global_load_lds(
                (const __attribute__((address_space(1))) unsigned int*)gb,
                (__attribute__((address_space(3))) unsigned int*)(Bs + (i * 256 + w * 64) * 8),
                16, 0, 0);
        }
        __syncthreads();
        s16x8 af[4], bf[4];
        #pragma unroll
        for (int i = 0; i < 4; ++i)
            af[i] = *(const s16x8*)(As + (wm + i * 16 + lrow) * 32 + lq * 8);
        #pragma unroll
        for (int j = 0; j < 4; ++j)
            bf[j] = *(const s16x8*)(Bs + (wn + j * 16 + lrow) * 32 + lq * 8);
        #pragma unroll
        for (int i = 0; i < 4; ++i)
            #pragma unroll
            for (int j = 0; j < 4; ++j)
                acc[i][j] = __builtin_amdgcn_mfma_f32_16x16x32_bf16(af[i], bf[j], acc[i][j], 0, 0, 0);
    }
    #pragma unroll
    for (int j = 0; j < 4; ++j) {
        long col = n0 + wn + j * 16 + lrow;
        float bv = bias[col];
        #pragma unroll
        for (int i = 0; i < 4; ++i) {
            long rowb = m0 + wm + i * 16 + lq * 4;
            #pragma unroll
            for (int r = 0; r < 4; ++r) {
                float v = acc[i][j][r] + bv;
                long row = rowb + r;
                if (xperm) {
                    long t = row >> 6, b = row & 63;
                    long g = col >> 10, h = col & 1023;
                    Cb[t * 262144 + (h >> 4) * 4096 + b * 64 + g * 16 + (h & 15)] = f2b(v);
                } else {
                    Cf[row * (long)ldc + col] = v;
                }
            }
        }
    }
}

// ---------- persistent LSTM recurrence: 64 WGs, 1 barrier/step ----------
// WG j owns cols c = g*16+hi (4 gates x 16 h), h = 16j+hi.
// Wave (bt,ct): bt = 32-row half, ct = 512-K half; each wave computes a PARTIAL
// 32x64 G tile over its K half (zero A duplication), with its 64 W fragments held
// in REGISTERS for all 256 steps (no per-step LDS W reads, no W staging).
// H lives in Hp layout [t][k>>4][b][k&15]: A-loads are 1-KB contiguous bursts and
// H stores are 128-B contiguous per wave-instr (full-line write-through).
// Gbuf: col-major [2 halves][64 cols][64 rows] f32, rows XOR-swizzled by col for
// conflict-free ds_write_b128 of accumulators; pointwise sums both K halves.
// Coherence: write-through H stores (sc0 sc1); NO per-step cache maintenance.
// L2 warming: 8 co-XCD WGs each stream 1/8 of H_t (contiguous) into Gbuf-scratch.
__global__ __launch_bounds__(256, 1) void lstm_steps(const u16* __restrict__ Xp,
                                                     const u16* __restrict__ Wpack,
                                                     const float* __restrict__ C0,
                                                     u16* __restrict__ HsBuf,
                                                     float* __restrict__ out,
                                                     unsigned* __restrict__ cnt) {
    extern __shared__ char smem[];
    float* Gbuf = (float*)smem;               // 2*64*64 f32 = 32768 B (also warm scratch)
    const int tid  = threadIdx.x;
    const int lane = tid & 63;
    const int w    = tid >> 6;
    const int j    = blockIdx.x;
    const int ln   = lane & 31;
    const int kh   = lane >> 5;
    const int bt   = w >> 1;     // row half (32 rows)
    const int ct   = w & 1;      // K half (512 k)

    // ---- this wave's 64 W fragments -> registers, held for all 256 steps ----
    s16x8 bfr0[32], bfr1[32];
    {
        const uint4* wj = (const uint4*)Wpack + (size_t)j * 8192 + (size_t)ct * 2048 + lane;
        #pragma unroll
        for (int kk = 0; kk < 32; ++kk) {
            bfr0[kk] = *(const s16x8*)(wj + (size_t)kk * 64);          // col-tile 0
            bfr1[kk] = *(const s16x8*)(wj + 4096 + (size_t)kk * 64);   // col-tile 1
        }
    }

    const int phi = tid & 15, pbq = tid >> 4;
    const int h = 16 * j + phi;
    float c_reg[4];
    #pragma unroll
    for (int r = 0; r < 4; ++r) c_reg[r] = C0[(size_t)(16 * r + pbq) * 1024 + h];

    unsigned* leaf = cnt + (j & 7) * 32;   // 8 leaves, 128 B apart
    unsigned* root = cnt + 512;            // separate line
    const int slice = j >> 3;              // co-XCD WGs (j%8 alike) cover 8 distinct slices
    const int swz = (ln & 7) << 2;

    for (int t = 0; t < T_LEN; ++t) {
        const u16* Hbase = HsBuf + (size_t)t * 65536;

        // --- warm XCD-L2 with our 16 KB slice of H_t (fire-and-forget into scratch) ---
        #pragma unroll
        for (int i = 0; i < 4; ++i) {
            const u16* gp = Hbase + (size_t)slice * 8192 + (size_t)w * 2048 + i * 512 + lane * 8;
            __builtin_amdgcn_global_load_lds(
                (const __attribute__((address_space(1))) unsigned int*)gp,
                (__attribute__((address_space(3))) unsigned int*)
                    ((char*)Gbuf + w * 4096 + i * 1024),
                16, 0, 0);
        }

        // --- X gathers (contiguous 8 KB block per WG) ---
        const u16* xb = Xp + (size_t)t * 262144 + (size_t)j * 4096;
        u16 xv[4][4];
        #pragma unroll
        for (int r = 0; r < 4; ++r) {
            int b = 16 * r + pbq;
            #pragma unroll
            for (int g = 0; g < 4; ++g)
                xv[r][g] = xb[b * 64 + g * 16 + phi];
        }

        // --- MFMA: partial G over this wave's K half; A-loads 1-KB coalesced ---
        const u16* hb2 = Hbase + (size_t)ct * 32768 + (size_t)(bt * 32 + ln) * 16 + kh * 8;
        f32x16 acc0 = {};
        f32x16 acc1 = {};
        #pragma unroll
        for (int cc = 0; cc < 4; ++cc) {
            s16x8 av[8];
            #pragma unroll
            for (int u = 0; u < 8; ++u)
                av[u] = *(const s16x8*)(hb2 + (size_t)(cc * 8 + u) * 1024);
            #pragma unroll
            for (int u = 0; u < 8; ++u) {
                acc0 = __builtin_amdgcn_mfma_f32_32x32x16_bf16(av[u], bfr0[cc * 8 + u], acc0, 0, 0, 0);
                acc1 = __builtin_amdgcn_mfma_f32_32x32x16_bf16(av[u], bfr1[cc * 8 + u], acc1, 0, 0, 0);
            }
        }
        // all warm-DMA into Gbuf scratch must land before real G writes (all waves)
        asm volatile("s_waitcnt vmcnt(0)" ::: "memory");
        __syncthreads();
        {   // col-major swizzled partial-G store: 8x ds_write_b128 per wave
            // C/D layout 32x32: col = lane&31, row = (reg&3) + 8*(reg>>2) + 4*(lane>>5)
            float* Gp = Gbuf + (size_t)ct * 4096 + (size_t)ln * 64 + bt * 32;
            #pragma unroll
            for (int q = 0; q < 4; ++q) {
                int rs = (8 * q + 4 * kh) ^ swz;
                f32x4 v0 = {acc0[4 * q], acc0[4 * q + 1], acc0[4 * q + 2], acc0[4 * q + 3]};
                f32x4 v1 = {acc1[4 * q], acc1[4 * q + 1], acc1[4 * q + 2], acc1[4 * q + 3]};
                *(f32x4*)(Gp + rs)        = v0;   // cols [0,32)
                *(f32x4*)(Gp + 2048 + rs) = v1;   // cols [32,64)
            }
        }
        __syncthreads();

        // --- pointwise (sum K halves) + write-through H stores (contiguous) ---
        const float* gcol = Gbuf + (size_t)phi * 64;
        const int psw = (phi & 7) << 2;
        #pragma unroll
        for (int r = 0; r < 4; ++r) {
            int b  = 16 * r + pbq;
            int bs = b ^ psw;
            float I  = sigmoidf_(gcol[bs]        + gcol[4096 + bs] + b2f(xv[r][0]));
            float F  = sigmoidf_(gcol[1024 + bs] + gcol[5120 + bs] + b2f(xv[r][1]));
            float O  = sigmoidf_(gcol[2048 + bs] + gcol[6144 + bs] + b2f(xv[r][2]));
            float Ct = tanhf_   (gcol[3072 + bs] + gcol[7168 + bs] + b2f(xv[r][3]));
            float cn = F * c_reg[r] + I * Ct;
            c_reg[r] = cn;
            float hn = O * tanhf_(cn);
            unsigned hb = f2b(hn);
            u16* dst = HsBuf + (size_t)(t + 1) * 65536 + (size_t)j * 1024 + r * 256 + tid;
            asm volatile("global_store_short %0, %1, off sc0 sc1"
                         :: "v"(dst), "v"(hb) : "memory");
            if (t == T_LEN - 1) {
                out[16777216 + (size_t)b * 1024 + h] = hn;            // Hf
                out[16777216 + 65536 + (size_t)b * 1024 + h] = cn;    // Cf
            }
        }
        if (t == T_LEN - 1) break;

        // release: drain asm stores, sync waves, then device barrier
        asm volatile("s_waitcnt vmcnt(0)" ::: "memory");
        __syncthreads();
        if (tid == 0) {
            unsigned old = __hip_atomic_fetch_add(leaf, 1u, __ATOMIC_RELAXED,
                                                  __HIP_MEMORY_SCOPE_AGENT);
            if (old == 8u * (unsigned)t + 7u)
                __hip_atomic_fetch_add(root, 1u, __ATOMIC_RELAXED, __HIP_MEMORY_SCOPE_AGENT);
            unsigned tgt = 8u * (unsigned)(t + 1);
            while (__hip_atomic_load(root, __ATOMIC_RELAXED, __HIP_MEMORY_SCOPE_AGENT) < tgt)
                __builtin_amdgcn_s_sleep(2);
        }
        __syncthreads();
    }
}

// ---------- workspace layout (bytes) ----------
//   0         : cnt[1024] (leaves at dword (j&7)*32, root at dword 512)   4096 B
//   4096      : fused bias f32[4096]                                     16384 B
//   20480     : 9 transposed bf16 weights, 2 MB each (Wxi..Wxc, Whi..Whc, Whq)
//   18894848  : Wpack bf16, MFMA-frag order                            8388608 B
//   27283456  : Xbf  bf16 [16384][1024]                               33554432 B
//   60837888  : Xp   bf16 permuted [t][h>>4][b][g][h&15]             134217728 B
//   195055616 : HsBuf bf16 [257] chunks, Hp layout [k>>4][b][k&15]    33685504 B
extern "C" void kernel_launch(void* const* d_in, const int* in_sizes, int n_in,
                              void* d_out, int out_size, void* d_ws, size_t ws_size,
                              hipStream_t stream) {
    const float* inputs = (const float*)d_in[0];
    const float* H0   = (const float*)d_in[1];
    const float* C0   = (const float*)d_in[2];
    const float* W_xi = (const float*)d_in[3];
    const float* W_hi = (const float*)d_in[4];
    const float* b_i  = (const float*)d_in[5];
    const float* W_xf = (const float*)d_in[6];
    const float* W_hf = (const float*)d_in[7];
    const float* b_f  = (const float*)d_in[8];
    const float* W_xo = (const float*)d_in[9];
    const float* W_ho = (const float*)d_in[10];
    const float* b_o  = (const float*)d_in[11];
    const float* W_xc = (const float*)d_in[12];
    const float* W_hc = (const float*)d_in[13];
    const float* b_c  = (const float*)d_in[14];
    const float* W_hq = (const float*)d_in[15];
    const float* b_q  = (const float*)d_in[16];

    float* out = (float*)d_out;
    char* ws = (char*)d_ws;
    unsigned* cnt  = (unsigned*)ws;
    float* fbias   = (float*)(ws + 4096);
    u16* WT        = (u16*)(ws + 20480);
    u16* Wpack     = (u16*)(ws + 18894848);
    u16* Xbf       = (u16*)(ws + 27283456);
    u16* Xp        = (u16*)(ws + 60837888);
    u16* HsBuf     = (u16*)(ws + 195055616);

    f32_to_bf16<<<16384, 256, 0, stream>>>((const float4*)inputs, (ushort4*)Xbf, 4194304);

    const float* wsrcs[9] = {W_xi, W_xf, W_xo, W_xc, W_hi, W_hf, W_ho, W_hc, W_hq};
    for (int i = 0; i < 9; ++i)
        transpose_f32_bf16<<<dim3(16, 16), 256, 0, stream>>>(wsrcs[i], WT + (size_t)i * 1048576);

    init_misc<<<256, 256, 0, stream>>>(H0, HsBuf, cnt, b_i, b_f, b_o, b_c, fbias);
    pack_wh<<<2048, 256, 0, stream>>>(WT + (size_t)4 * 1048576, Wpack);

    // fused input projection -> permuted X layout
    gemm_bt<<<dim3(128, 32), 256, 0, stream>>>(Xbf, WT, fbias, Xp, (float*)nullptr,
                                               16384, 1024, 4096, 1, 0);

    lstm_steps<<<NWG, 256, 32768, stream>>>(Xp, Wpack, C0, HsBuf, out, cnt);

    // outputs = Hs @ W_hq + b_q (fp32 out), A in Hp layout
    gemm_bt<<<dim3(128, 8), 256, 0, stream>>>(HsBuf + 65536, WT + (size_t)8 * 1048576, b_q,
                                              (u16*)nullptr, out, 16384, 1024, 1024, 0, 1);
}

// Round 2
// 2574.193 us; speedup vs baseline: 1.4003x; 1.4003x over previous
//
#include <hip/hip_runtime.h>
#include <cstdint>

typedef unsigned short u16;
typedef __attribute__((ext_vector_type(8))) short s16x8;    // 8 bf16 (4 VGPRs)
typedef __attribute__((ext_vector_type(4))) float f32x4;    // 16x16 MFMA C/D frag
typedef __attribute__((ext_vector_type(16))) float f32x16;  // 32x32 MFMA C/D frag

#define T_LEN 256
#define BATCH 64
#define HID   1024
#define NWG   64
#define GLD   65     // Gbuf leading dim (f32): conflict-free

// ---------- bf16 helpers ----------
__device__ __forceinline__ float b2f(u16 u) {
    union { unsigned u; float f; } v; v.u = ((unsigned)u) << 16; return v.f;
}
__device__ __forceinline__ u16 f2b(float f) {
    union { float f; unsigned u; } v; v.f = f;
    unsigned u = v.u;
    return (u16)((u + 0x7fffu + ((u >> 16) & 1u)) >> 16);
}
__device__ __forceinline__ float sigmoidf_(float x) { return 1.0f / (1.0f + __expf(-x)); }
__device__ __forceinline__ float tanhf_(float x) {
    float e = __expf(2.0f * x);
    return 1.0f - 2.0f / (e + 1.0f);
}

// ---------- fp32 -> bf16 bulk convert ----------
__global__ __launch_bounds__(256) void f32_to_bf16(const float4* __restrict__ in,
                                                   ushort4* __restrict__ out, int n4) {
    int i = blockIdx.x * 256 + threadIdx.x;
    if (i < n4) {
        float4 v = in[i];
        ushort4 o;
        o.x = f2b(v.x); o.y = f2b(v.y); o.z = f2b(v.z); o.w = f2b(v.w);
        out[i] = o;
    }
}

// ---------- transpose 1024x1024: out_bf16[c][r] = (bf16)in_f32[r][c] ----------
__global__ __launch_bounds__(256) void transpose_f32_bf16(const float* __restrict__ in,
                                                          u16* __restrict__ out) {
    __shared__ u16 tile[64][65];
    int tx = threadIdx.x & 63, ty = threadIdx.x >> 6;
    int r0 = blockIdx.y * 64, c0 = blockIdx.x * 64;
    for (int r = ty; r < 64; r += 4)
        tile[r][tx] = f2b(in[(size_t)(r0 + r) * 1024 + c0 + tx]);
    __syncthreads();
    for (int c = ty; c < 64; c += 4)
        out[(size_t)(c0 + c) * 1024 + r0 + tx] = tile[tx][c];
}

// ---------- init: counters, fused bias, HsBuf[0] = (bf16)H0 in Hp layout ----------
// Hp layout per step-chunk (65536 u16): off(b,k) = (k>>4)*1024 + b*16 + (k&15)
__global__ __launch_bounds__(256) void init_misc(const float* __restrict__ H0,
                                                 u16* __restrict__ HsBuf,
                                                 unsigned* __restrict__ cnt,
                                                 const float* __restrict__ b_i,
                                                 const float* __restrict__ b_f,
                                                 const float* __restrict__ b_o,
                                                 const float* __restrict__ b_c,
                                                 float* __restrict__ fbias) {
    int i = blockIdx.x * 256 + threadIdx.x;   // grid 256x256 = 65536
    if (i < 1024) cnt[i] = 0u;
    if (i < 4096) {
        int g = i >> 10, k = i & 1023;
        const float* bp = (g == 0) ? b_i : (g == 1) ? b_f : (g == 2) ? b_o : b_c;
        fbias[i] = bp[k];
    }
    if (i < BATCH * HID) {
        int b = i >> 10, k = i & 1023;
        HsBuf[(size_t)(k >> 4) * 1024 + b * 16 + (k & 15)] = f2b(H0[i]);
    }
}

// ---------- pack W_h (4 mats, [h][k] transposed layout) into MFMA-frag order ----
__global__ __launch_bounds__(256) void pack_wh(const u16* __restrict__ WThT,
                                               u16* __restrict__ Wpack) {
    size_t idx = (size_t)blockIdx.x * 256 + threadIdx.x;  // 0..524287
    int lane = idx & 63;
    int kc   = (idx >> 6) & 63;
    int ct   = (idx >> 12) & 1;
    int j    = (int)(idx >> 13);
    int ln = lane & 31, kh = lane >> 5;
    int col = ct * 32 + ln;
    int g = col >> 4, hi = col & 15;
    const uint4* src = (const uint4*)(WThT + (size_t)g * 1048576 +
                                      (size_t)(16 * j + hi) * 1024 + kc * 16 + kh * 8);
    ((uint4*)Wpack)[idx] = *src;
}

// ---------- GEMM: C[m][col] = A[m][:] . BT[col][:] + bias[col] ----------
// mode 0: Cf fp32 row-major [M][ldc].  mode 1: Cb bf16 permuted X layout
//   off(t,b,g,h) = t*262144 + (h>>4)*4096 + b*64 + g*16 + (h&15), row=t*64+b, col=g*1024+h
// aperm: A is in Hp layout (per-64-row chunk of 65536 u16, off = (k>>4)*1024 + b*16 + (k&15))
__global__ __launch_bounds__(256) void gemm_bt(const u16* __restrict__ A,
                                               const u16* __restrict__ BT,
                                               const float* __restrict__ bias,
                                               u16* __restrict__ Cb,
                                               float* __restrict__ Cf,
                                               int M, int K, int ldc, int xperm, int aperm) {
    __shared__ __align__(16) u16 As[128 * 32];
    __shared__ __align__(16) u16 Bs[128 * 32];
    const int tid  = threadIdx.x;
    const int lane = tid & 63;
    const int w    = tid >> 6;
    const int wm   = (w >> 1) * 64;
    const int wn   = (w & 1) * 64;
    const long m0 = (long)blockIdx.x * 128;
    const long n0 = (long)blockIdx.y * 128;
    const int lrow = lane & 15;
    const int lq   = lane >> 4;

    f32x4 acc[4][4];
    const f32x4 vzero = {0.f, 0.f, 0.f, 0.f};
    #pragma unroll
    for (int i = 0; i < 4; ++i)
        #pragma unroll
        for (int j = 0; j < 4; ++j) acc[i][j] = vzero;

    for (int k0 = 0; k0 < K; k0 += 32) {
        __syncthreads();
        #pragma unroll
        for (int i = 0; i < 2; ++i) {
            int chunk = i * 256 + w * 64 + lane;
            const u16* ga;
            if (aperm) {
                long row = m0 + (chunk >> 2);
                int  c   = chunk & 3;
                ga = A + (row >> 6) * 65536L + (long)((k0 >> 4) + (c >> 1)) * 1024 +
                     (row & 63) * 16 + (c & 1) * 8;
            } else {
                ga = A + (m0 + (chunk >> 2)) * (long)K + k0 + (chunk & 3) * 8;
            }
            __builtin_amdgcn_global_load_lds(
                (const __attribute__((address_space(1))) unsigned int*)ga,
                (__attribute__((address_space(3))) unsigned int*)(As + (i * 256 + w * 64) * 8),
                16, 0, 0);
            const u16* gb = BT + (n0 + (chunk >> 2)) * (long)K + k0 + (chunk & 3) * 8;
            __builtin_amdgcn_global_load_lds(
                (const __attribute__((address_space(1))) unsigned int*)gb,
                (__attribute__((address_space(3))) unsigned int*)(Bs + (i * 256 + w * 64) * 8),
                16, 0, 0);
        }
        __syncthreads();
        s16x8 af[4], bf[4];
        #pragma unroll
        for (int i = 0; i < 4; ++i)
            af[i] = *(const s16x8*)(As + (wm + i * 16 + lrow) * 32 + lq * 8);
        #pragma unroll
        for (int j = 0; j < 4; ++j)
            bf[j] = *(const s16x8*)(Bs + (wn + j * 16 + lrow) * 32 + lq * 8);
        #pragma unroll
        for (int i = 0; i < 4; ++i)
            #pragma unroll
            for (int j = 0; j < 4; ++j)
                acc[i][j] = __builtin_amdgcn_mfma_f32_16x16x32_bf16(af[i], bf[j], acc[i][j], 0, 0, 0);
    }
    #pragma unroll
    for (int j = 0; j < 4; ++j) {
        long col = n0 + wn + j * 16 + lrow;
        float bv = bias[col];
        #pragma unroll
        for (int i = 0; i < 4; ++i) {
            long rowb = m0 + wm + i * 16 + lq * 4;
            #pragma unroll
            for (int r = 0; r < 4; ++r) {
                float v = acc[i][j][r] + bv;
                long row = rowb + r;
                if (xperm) {
                    long t = row >> 6, b = row & 63;
                    long g = col >> 10, h = col & 1023;
                    Cb[t * 262144 + (h >> 4) * 4096 + b * 64 + g * 16 + (h & 15)] = f2b(v);
                } else {
                    Cf[row * (long)ldc + col] = v;
                }
            }
        }
    }
}

// ---------- persistent LSTM recurrence: 64 WGs, 1 barrier/step ----------
// WG j owns cols c = g*16+hi (4 gates x 16 h), h = 16j+hi.
// Wave (bt,ct): 32 b-rows x 32 cols, 32x32x16 MFMA, W frags lane-linear in LDS.
// H lives in Hp layout [t][k>>4][b][k&15]:
//   - A-frag loads are wave-contiguous 1 KB bursts (1 segment/instr vs 32)
//   - H stores are one contiguous 128 B segment per wave-instr (fast WT drain)
// Coherence: write-through H stores (sc0 sc1); NO per-step cache maintenance.
// L2 warming: 8 co-XCD WGs each stream 1/8 of H_t (contiguous) into Gbuf-scratch.
__global__ __launch_bounds__(256, 1) void lstm_steps(const u16* __restrict__ Xp,
                                                     const u16* __restrict__ Wpack,
                                                     const float* __restrict__ C0,
                                                     u16* __restrict__ HsBuf,
                                                     float* __restrict__ out,
                                                     unsigned* __restrict__ cnt) {
    extern __shared__ char smem[];
    u16*   Wlds = (u16*)smem;                 // 131072 B, frag-packed
    float* Gbuf = (float*)(smem + 131072);    // 64*65*4 = 16640 B (also warm scratch)
    const int tid  = threadIdx.x;
    const int lane = tid & 63;
    const int w    = tid >> 6;
    const int j    = blockIdx.x;
    const int ln   = lane & 31;
    const int kh   = lane >> 5;
    const int bt   = w >> 1;
    const int ct   = w & 1;

    {   // stage packed W slice (128 KB contiguous, coalesced)
        const uint4* wsrc = (const uint4*)Wpack + (size_t)j * 8192;
        uint4* wdst = (uint4*)Wlds;
        for (int i = tid; i < 8192; i += 256) wdst[i] = wsrc[i];
    }

    const int phi = tid & 15, pbq = tid >> 4;
    const int h = 16 * j + phi;
    float c_reg[4];
    #pragma unroll
    for (int r = 0; r < 4; ++r) c_reg[r] = C0[(size_t)(16 * r + pbq) * 1024 + h];
    __syncthreads();

    unsigned* leaf = cnt + (j & 7) * 32;   // 8 leaves, 128 B apart
    unsigned* root = cnt + 512;            // separate line
    const u16* wbase = Wlds + ct * 32768 + lane * 8;
    const int slice = j >> 3;              // co-XCD WGs (j%8 alike) cover 8 distinct slices

    for (int t = 0; t < T_LEN; ++t) {
        const u16* Hbase = HsBuf + (size_t)t * 65536;

        // --- warm XCD-L2 with our 16 KB slice of H_t (fire-and-forget into scratch) ---
        #pragma unroll
        for (int i = 0; i < 4; ++i) {
            const u16* gp = Hbase + (size_t)slice * 8192 + (size_t)w * 2048 + i * 512 + lane * 8;
            __builtin_amdgcn_global_load_lds(
                (const __attribute__((address_space(1))) unsigned int*)gp,
                (__attribute__((address_space(3))) unsigned int*)
                    ((char*)Gbuf + w * 4096 + i * 1024),
                16, 0, 0);
        }

        // --- X gathers (contiguous 8 KB block per WG) ---
        const u16* xb = Xp + (size_t)t * 262144 + (size_t)j * 4096;
        u16 xv[4][4];
        #pragma unroll
        for (int r = 0; r < 4; ++r) {
            int b = 16 * r + pbq;
            #pragma unroll
            for (int g = 0; g < 4; ++g)
                xv[r][g] = xb[b * 64 + g * 16 + phi];
        }

        // --- MFMA: G = H_t @ W slice; A-loads wave-contiguous 1 KB (Hp layout) ---
        const u16* hrow = Hbase + (size_t)(bt * 32 + ln) * 16 + kh * 8;
        f32x16 acc0 = {};
        f32x16 acc1 = {};
        #pragma unroll 8
        for (int kc = 0; kc < 64; kc += 2) {
            s16x8 a0 = *(const s16x8*)(hrow + (size_t)kc * 1024);
            s16x8 a1 = *(const s16x8*)(hrow + (size_t)kc * 1024 + 1024);
            s16x8 b0 = *(const s16x8*)(wbase + kc * 512);
            s16x8 b1 = *(const s16x8*)(wbase + kc * 512 + 512);
            acc0 = __builtin_amdgcn_mfma_f32_32x32x16_bf16(a0, b0, acc0, 0, 0, 0);
            acc1 = __builtin_amdgcn_mfma_f32_32x32x16_bf16(a1, b1, acc1, 0, 0, 0);
        }
        // all warm-DMA into Gbuf scratch must land before real G writes (all waves)
        asm volatile("s_waitcnt vmcnt(0)" ::: "memory");
        __syncthreads();
        // C/D layout 32x32: col = lane&31, row = (reg&3) + 8*(reg>>2) + 4*(lane>>5)
        #pragma unroll
        for (int r = 0; r < 16; ++r) {
            int row = bt * 32 + (r & 3) + 8 * (r >> 2) + 4 * kh;
            Gbuf[row * GLD + ct * 32 + ln] = acc0[r] + acc1[r];
        }
        __syncthreads();

        // --- pointwise + write-through H stores (contiguous 128 B/wave) ---
        #pragma unroll
        for (int r = 0; r < 4; ++r) {
            int b = 16 * r + pbq;
            const float* gb = Gbuf + b * GLD + phi;
            float I  = sigmoidf_(gb[0]  + b2f(xv[r][0]));
            float F  = sigmoidf_(gb[16] + b2f(xv[r][1]));
            float O  = sigmoidf_(gb[32] + b2f(xv[r][2]));
            float Ct = tanhf_   (gb[48] + b2f(xv[r][3]));
            float cn = F * c_reg[r] + I * Ct;
            c_reg[r] = cn;
            float hn = O * tanhf_(cn);
            unsigned hb = f2b(hn);
            u16* dst = HsBuf + (size_t)(t + 1) * 65536 + (size_t)j * 1024 + r * 256 + tid;
            asm volatile("global_store_short %0, %1, off sc0 sc1"
                         :: "v"(dst), "v"(hb) : "memory");
            if (t == T_LEN - 1) {
                out[16777216 + (size_t)b * 1024 + h] = hn;            // Hf
                out[16777216 + 65536 + (size_t)b * 1024 + h] = cn;    // Cf
            }
        }
        if (t == T_LEN - 1) break;

        // release: drain asm stores, sync waves, then device barrier
        asm volatile("s_waitcnt vmcnt(0)" ::: "memory");
        __syncthreads();
        if (tid == 0) {
            unsigned old = __hip_atomic_fetch_add(leaf, 1u, __ATOMIC_RELAXED,
                                                  __HIP_MEMORY_SCOPE_AGENT);
            if (old == 8u * (unsigned)t + 7u)
                __hip_atomic_fetch_add(root, 1u, __ATOMIC_RELAXED, __HIP_MEMORY_SCOPE_AGENT);
            unsigned tgt = 8u * (unsigned)(t + 1);
            while (__hip_atomic_load(root, __ATOMIC_RELAXED, __HIP_MEMORY_SCOPE_AGENT) < tgt)
                __builtin_amdgcn_s_sleep(2);
        }
        __syncthreads();
    }
}

// ---------- workspace layout (bytes) ----------
//   0         : cnt[1024] (leaves at dword (j&7)*32, root at dword 512)   4096 B
//   4096      : fused bias f32[4096]                                     16384 B
//   20480     : 9 transposed bf16 weights, 2 MB each (Wxi..Wxc, Whi..Whc, Whq)
//   18894848  : Wpack bf16, MFMA-frag order                            8388608 B
//   27283456  : Xbf  bf16 [16384][1024]                               33554432 B
//   60837888  : Xp   bf16 permuted [t][h>>4][b][g][h&15]             134217728 B
//   195055616 : HsBuf bf16 [257] chunks, Hp layout [k>>4][b][k&15]    33685504 B
extern "C" void kernel_launch(void* const* d_in, const int* in_sizes, int n_in,
                              void* d_out, int out_size, void* d_ws, size_t ws_size,
                              hipStream_t stream) {
    const float* inputs = (const float*)d_in[0];
    const float* H0   = (const float*)d_in[1];
    const float* C0   = (const float*)d_in[2];
    const float* W_xi = (const float*)d_in[3];
    const float* W_hi = (const float*)d_in[4];
    const float* b_i  = (const float*)d_in[5];
    const float* W_xf = (const float*)d_in[6];
    const float* W_hf = (const float*)d_in[7];
    const float* b_f  = (const float*)d_in[8];
    const float* W_xo = (const float*)d_in[9];
    const float* W_ho = (const float*)d_in[10];
    const float* b_o  = (const float*)d_in[11];
    const float* W_xc = (const float*)d_in[12];
    const float* W_hc = (const float*)d_in[13];
    const float* b_c  = (const float*)d_in[14];
    const float* W_hq = (const float*)d_in[15];
    const float* b_q  = (const float*)d_in[16];

    float* out = (float*)d_out;
    char* ws = (char*)d_ws;
    unsigned* cnt  = (unsigned*)ws;
    float* fbias   = (float*)(ws + 4096);
    u16* WT        = (u16*)(ws + 20480);
    u16* Wpack     = (u16*)(ws + 18894848);
    u16* Xbf       = (u16*)(ws + 27283456);
    u16* Xp        = (u16*)(ws + 60837888);
    u16* HsBuf     = (u16*)(ws + 195055616);

    f32_to_bf16<<<16384, 256, 0, stream>>>((const float4*)inputs, (ushort4*)Xbf, 4194304);

    const float* wsrcs[9] = {W_xi, W_xf, W_xo, W_xc, W_hi, W_hf, W_ho, W_hc, W_hq};
    for (int i = 0; i < 9; ++i)
        transpose_f32_bf16<<<dim3(16, 16), 256, 0, stream>>>(wsrcs[i], WT + (size_t)i * 1048576);

    init_misc<<<256, 256, 0, stream>>>(H0, HsBuf, cnt, b_i, b_f, b_o, b_c, fbias);
    pack_wh<<<2048, 256, 0, stream>>>(WT + (size_t)4 * 1048576, Wpack);

    // fused input projection -> permuted X layout
    gemm_bt<<<dim3(128, 32), 256, 0, stream>>>(Xbf, WT, fbias, Xp, (float*)nullptr,
                                               16384, 1024, 4096, 1, 0);

    (void)hipFuncSetAttribute((const void*)lstm_steps,
                              hipFuncAttributeMaxDynamicSharedMemorySize, 147712);
    lstm_steps<<<NWG, 256, 147712, stream>>>(Xp, Wpack, C0, HsBuf, out, cnt);

    // outputs = Hs @ W_hq + b_q (fp32 out), A in Hp layout
    gemm_bt<<<dim3(128, 8), 256, 0, stream>>>(HsBuf + 65536, WT + (size_t)8 * 1048576, b_q,
                                              (u16*)nullptr, out, 16384, 1024, 1024, 0, 1);
}